// Round 2
// baseline (830.920 us; speedup 1.0000x reference)
//
#include <hip/hip_runtime.h>

typedef unsigned short ushort_t;
typedef float  f32x4  __attribute__((ext_vector_type(4)));
typedef __bf16 bf16x8 __attribute__((ext_vector_type(8)));

#define MFMA16(a,b,c) __builtin_amdgcn_mfma_f32_16x16x32_bf16((a),(b),(c),0,0,0)

__device__ __forceinline__ ushort_t f2bf(float f) {
  union { float f; unsigned u; } v; v.f = f;
  unsigned u = v.u;
  unsigned r = u + 0x7FFFu + ((u >> 16) & 1u);   // round-to-nearest-even
  return (ushort_t)(r >> 16);
}
__device__ __forceinline__ float bf2f(ushort_t s) {
  union { unsigned u; float f; } v; v.u = ((unsigned)s) << 16;
  return v.f;
}

// ---------------------------------------------------------------------------
// Kernel 1: fused grouped conv (MFMA) + bias; x staged once per block (f32 ->
// bf16 transpose in LDS), loops 3 branches x 4 ngsub. Writes unnormalized y
// in final layouts; accumulates GroupNorm partial sums via atomics.
// grid (pc=16, g*b=64), 256 thr.
// Q branch -> [B][C][P]; K/V branches -> [B][H][P][128].
// ---------------------------------------------------------------------------
__global__ __launch_bounds__(256) void conv_gn(
    const float* __restrict__ x,
    const float* __restrict__ wq, const float* __restrict__ wk, const float* __restrict__ wv,
    const float* __restrict__ bq, const float* __restrict__ bk, const float* __restrict__ bv,
    ushort_t* __restrict__ Qb, ushort_t* __restrict__ Kb, ushort_t* __restrict__ Vb,
    float* __restrict__ stats) {
  int pc = blockIdx.x;
  int gz = blockIdx.y;
  int b = gz & 7, g = gz >> 3;
  int tid = threadIdx.x, lane = tid & 63, wid = tid >> 6;
  int l15 = lane & 15, q = lane >> 4;

  __shared__ __align__(16) ushort_t xl[128 * 72];   // [p][f]
  __shared__ __align__(16) ushort_t wl[128 * 72];   // [co][f], one branch
  __shared__ __align__(16) ushort_t yl[128 * 40];   // staging (br=0 uses [32][136])
  __shared__ float biasl[128];
  __shared__ float redbuf[8];

  // stage x tile [64 f][128 p] f32 -> xl[p][f] bf16
  const float* xsrc = x + ((size_t)(b * 512 + g * 64)) * 2048 + pc * 128;
#pragma unroll
  for (int r = 0; r < 8; ++r) {
    int chunk = tid + 256 * r;
    int c = chunk >> 5, p4 = chunk & 31;
    float4 v = *(const float4*)&xsrc[(size_t)c * 2048 + p4 * 4];
    xl[(p4 * 4 + 0) * 72 + c] = f2bf(v.x);
    xl[(p4 * 4 + 1) * 72 + c] = f2bf(v.y);
    xl[(p4 * 4 + 2) * 72 + c] = f2bf(v.z);
    xl[(p4 * 4 + 3) * 72 + c] = f2bf(v.w);
  }
  __syncthreads();

  // resident B-frags (wave's 32 p-cols)
  bf16x8 Bx[2][2];
#pragma unroll
  for (int n2 = 0; n2 < 2; ++n2)
#pragma unroll
    for (int kk = 0; kk < 2; ++kk)
      Bx[n2][kk] = *(const bf16x8*)&xl[((wid * 2 + n2) * 16 + l15) * 72 + kk * 32 + q * 8];

  for (int br = 0; br < 3; ++br) {
    const float* w    = (br == 0) ? wq : ((br == 1) ? wk : wv);
    const float* bias = (br == 0) ? bq : ((br == 1) ? bk : bv);
    ushort_t* dst     = (br == 0) ? Qb : ((br == 1) ? Kb : Vb);
    __syncthreads();   // previous branch's wl/yl consumers done
    const float* wsrc = w + (size_t)g * 128 * 64;
#pragma unroll
    for (int r = 0; r < 8; ++r) {
      int idx = (tid + 256 * r) << 2;
      float4 v = *(const float4*)&wsrc[idx];
      int row = idx >> 6, f = idx & 63;
      wl[row * 72 + f + 0] = f2bf(v.x);
      wl[row * 72 + f + 1] = f2bf(v.y);
      wl[row * 72 + f + 2] = f2bf(v.z);
      wl[row * 72 + f + 3] = f2bf(v.w);
    }
    if (tid < 128) biasl[tid] = bias[g * 128 + tid];
    __syncthreads();

    for (int ngs = 0; ngs < 4; ++ngs) {
      int co0 = ngs * 32;
      bf16x8 Aw[2][2];
#pragma unroll
      for (int m = 0; m < 2; ++m)
#pragma unroll
        for (int kk = 0; kk < 2; ++kk)
          Aw[m][kk] = *(const bf16x8*)&wl[(co0 + m * 16 + l15) * 72 + kk * 32 + q * 8];
      f32x4 acc[2][2];
#pragma unroll
      for (int m = 0; m < 2; ++m)
#pragma unroll
        for (int n2 = 0; n2 < 2; ++n2) acc[m][n2] = (f32x4){0.f, 0.f, 0.f, 0.f};
#pragma unroll
      for (int kk = 0; kk < 2; ++kk)
#pragma unroll
        for (int n2 = 0; n2 < 2; ++n2)
#pragma unroll
          for (int m = 0; m < 2; ++m)
            acc[m][n2] = MFMA16(Aw[m][kk], Bx[n2][kk], acc[m][n2]);

      float s1 = 0.f, s2 = 0.f;
#pragma unroll
      for (int m = 0; m < 2; ++m)
#pragma unroll
        for (int n2 = 0; n2 < 2; ++n2)
#pragma unroll
          for (int rg = 0; rg < 4; ++rg) {
            float y = acc[m][n2][rg] + biasl[co0 + m * 16 + 4 * q + rg];
            acc[m][n2][rg] = y;
            s1 += y; s2 += y * y;
          }
#pragma unroll
      for (int mask = 32; mask >= 1; mask >>= 1) {
        s1 += __shfl_xor(s1, mask, 64);
        s2 += __shfl_xor(s2, mask, 64);
      }

      __syncthreads();   // previous ngs's yl global-store reads done
      if (lane == 0) { redbuf[wid * 2] = s1; redbuf[wid * 2 + 1] = s2; }
      if (br == 0) {   // yl: [32 c][136 p]
#pragma unroll
        for (int m = 0; m < 2; ++m)
#pragma unroll
          for (int n2 = 0; n2 < 2; ++n2)
#pragma unroll
            for (int rg = 0; rg < 4; ++rg)
              yl[(m * 16 + 4 * q + rg) * 136 + (wid * 2 + n2) * 16 + l15] = f2bf(acc[m][n2][rg]);
      } else {         // yl: [128 p][40 c]
#pragma unroll
        for (int m = 0; m < 2; ++m)
#pragma unroll
          for (int n2 = 0; n2 < 2; ++n2)
#pragma unroll
            for (int rg = 0; rg < 4; ++rg)
              yl[((wid * 2 + n2) * 16 + l15) * 40 + m * 16 + 4 * q + rg] = f2bf(acc[m][n2][rg]);
      }
      __syncthreads();

      if (br == 0) {
#pragma unroll
        for (int r = 0; r < 2; ++r) {
          int chunk = tid + 256 * r;
          int row = chunk >> 4, ch = chunk & 15;
          *(uint4*)&dst[((size_t)(b * 1024 + g * 128 + co0 + row)) * 2048 + pc * 128 + ch * 8] =
              *(const uint4*)&yl[row * 136 + ch * 8];
        }
      } else {
#pragma unroll
        for (int r = 0; r < 2; ++r) {
          int chunk = tid + 256 * r;
          int row = chunk >> 2, ch = chunk & 3;
          *(uint4*)&dst[((size_t)(b * 8 + g) * 2048 + pc * 128 + row) * 128 + co0 + ch * 8] =
              *(const uint4*)&yl[row * 40 + ch * 8];
        }
      }
      if (tid == 0) {
        float S1 = redbuf[0] + redbuf[2] + redbuf[4] + redbuf[6];
        float S2 = redbuf[1] + redbuf[3] + redbuf[5] + redbuf[7];
        int sidx = (br * 8 + b) * 32 + g * 4 + ngs;
        atomicAdd(&stats[2 * sidx], S1);
        atomicAdd(&stats[2 * sidx + 1], S2);
      }
    }
  }
}

// ---------------------------------------------------------------------------
// Kernel 2: in-place GroupNorm affine + LeakyReLU over the 3 contiguous bufs.
// ---------------------------------------------------------------------------
__global__ __launch_bounds__(256) void gn_apply(
    ushort_t* __restrict__ buf, const float* __restrict__ stats,
    const float* __restrict__ gw1, const float* __restrict__ gb1,
    const float* __restrict__ gw2, const float* __restrict__ gb2,
    const float* __restrict__ gw3, const float* __restrict__ gb3) {
  const unsigned NQ = 16777216u;
  unsigned gid = blockIdx.x * 256 + threadIdx.x;
  unsigned e = gid * 8;
  int br; unsigned local;
  if (e < NQ)            { br = 0; local = e; }
  else if (e < 2u * NQ)  { br = 1; local = e - NQ; }
  else                   { br = 2; local = e - 2u * NQ; }
  int b, c0;
  if (br == 0) { b = local >> 21; c0 = (local >> 11) & 1023; }
  else {
    int cih = local & 127; int h = (local >> 18) & 7;
    b = local >> 21; c0 = h * 128 + cih;
  }
  int ng = c0 >> 5;
  const float* gw = (br == 0) ? gw1 : ((br == 1) ? gw2 : gw3);
  const float* gb = (br == 0) ? gb1 : ((br == 1) ? gb2 : gb3);
  int sidx = (br * 8 + b) * 32 + ng;
  float mean = stats[2 * sidx] * (1.f / 65536.f);
  float var  = stats[2 * sidx + 1] * (1.f / 65536.f) - mean * mean;
  float rstd = rsqrtf(var + 1e-5f);
  uint4 d = *(uint4*)&buf[(size_t)e];
  ushort_t* pu = (ushort_t*)&d;
#pragma unroll
  for (int i = 0; i < 8; ++i) {
    int ci = (br == 0) ? c0 : (c0 + i);
    float a = rstd * gw[ci];
    float b2 = gb[ci] - mean * a;
    float yn = fmaf(bf2f(pu[i]), a, b2);
    yn = (yn >= 0.f) ? yn : 0.1f * yn;
    pu[i] = f2bf(yn);
  }
  *(uint4*)&buf[(size_t)e] = d;
}

// ---------------------------------------------------------------------------
// Kernel 3: flash attention, S^T formulation.
// flashQ=K-branch [B,H,P,128] (i), flashK=V-branch [B,H,P,128] (j),
// flashV=Q-branch [B,C,P]. i-tile 128, j-tile 64.
// S^T = fK . fQ^T puts softmax dim (j) on C-layout rows: in-lane reduction +
// 2 shuffles; P exits with j contiguous in registers -> packed b64 LDS writes.
// Each wave owns 32 i-columns (softmax state) and the same 32 i-rows of O.
// ---------------------------------------------------------------------------
__global__ __launch_bounds__(256, 4) void attn(
    const ushort_t* __restrict__ Qb, const ushort_t* __restrict__ Kb,
    const ushort_t* __restrict__ Vb, float* __restrict__ out) {
  __shared__ __align__(16) ushort_t smem[35840];   // 71680 B
  ushort_t* Qs  = smem;            // [128 i][136] flashQ tile (resident)
  ushort_t* Vs  = smem + 17408;    // [128 c][72]  flashV tile, [c][j]
  ushort_t* KPs = smem + 26624;    // union: Ks [64 j][136] / Ps [128 i][72]
  float* Os = (float*)smem;        // [128][132] epilogue staging

  int it = blockIdx.x, bh = blockIdx.y;
  int tid = threadIdx.x, lane = tid & 63, wid = tid >> 6;
  int l15 = lane & 15, q = lane >> 4;
  const float scale = 0.08838834764831845f;   // 1/sqrt(128)

  const ushort_t* fQ = Kb + ((size_t)bh * 2048 + it * 128) * 128;
#pragma unroll
  for (int r = 0; r < 8; ++r) {
    int chunk = tid + 256 * r;
    int row = chunk >> 4, ch = chunk & 15;
    *(uint4*)&Qs[row * 136 + ch * 8] = *(const uint4*)&fQ[(size_t)row * 128 + ch * 8];
  }
  __syncthreads();

  bf16x8 Bq[2][4];   // resident flashQ B-frags (wave's 32 i-cols)
#pragma unroll
  for (int nt = 0; nt < 2; ++nt)
#pragma unroll
    for (int kk = 0; kk < 4; ++kk)
      Bq[nt][kk] = *(const bf16x8*)&Qs[((wid * 2 + nt) * 16 + l15) * 136 + kk * 32 + q * 8];

  float mrow[2], lrow[2];
  f32x4 O[2][8];
#pragma unroll
  for (int nt = 0; nt < 2; ++nt) { mrow[nt] = -1e30f; lrow[nt] = 0.f; }
#pragma unroll
  for (int mo = 0; mo < 2; ++mo)
#pragma unroll
    for (int cn = 0; cn < 8; ++cn) O[mo][cn] = (f32x4){0.f, 0.f, 0.f, 0.f};

  for (int jt = 0; jt < 32; ++jt) {
    const ushort_t* fK = Vb + ((size_t)bh * 2048 + jt * 64) * 128;
    const ushort_t* fV = Qb + (size_t)bh * 128 * 2048 + jt * 64;
#pragma unroll
    for (int r = 0; r < 4; ++r) {
      int chunk = tid + 256 * r;
      { int row = chunk >> 4, ch = chunk & 15;
        *(uint4*)&KPs[row * 136 + ch * 8] = *(const uint4*)&fK[(size_t)row * 128 + ch * 8]; }
      { int row = chunk >> 3, ch = chunk & 7;
        *(uint4*)&Vs[row * 72 + ch * 8] = *(const uint4*)&fV[(size_t)row * 2048 + ch * 8]; }
    }
    __syncthreads();   // #1

    // S^T[j][i]: A = fK rows (j), B = resident fQ frags (i)
    f32x4 ST[4][2];
#pragma unroll
    for (int mt = 0; mt < 4; ++mt)
#pragma unroll
      for (int nt = 0; nt < 2; ++nt) ST[mt][nt] = (f32x4){0.f, 0.f, 0.f, 0.f};
#pragma unroll
    for (int kk = 0; kk < 4; ++kk) {
      bf16x8 Ak[4];
#pragma unroll
      for (int mt = 0; mt < 4; ++mt)
        Ak[mt] = *(const bf16x8*)&KPs[(mt * 16 + l15) * 136 + kk * 32 + q * 8];
#pragma unroll
      for (int mt = 0; mt < 4; ++mt) {
        ST[mt][0] = MFMA16(Ak[mt], Bq[0][kk], ST[mt][0]);
        ST[mt][1] = MFMA16(Ak[mt], Bq[1][kk], ST[mt][1]);
      }
    }

    // online softmax over j (= C-layout rows): in-lane + 2 shuffles per i-col
    float al[2];
#pragma unroll
    for (int nt = 0; nt < 2; ++nt) {
      float v = ST[0][nt][0];
#pragma unroll
      for (int mt = 0; mt < 4; ++mt)
#pragma unroll
        for (int rg = 0; rg < 4; ++rg) v = fmaxf(v, ST[mt][nt][rg]);
      v *= scale;
      v = fmaxf(v, __shfl_xor(v, 16, 64));
      v = fmaxf(v, __shfl_xor(v, 32, 64));
      float mn = fmaxf(mrow[nt], v);
      al[nt] = __expf(mrow[nt] - mn);
      mrow[nt] = mn;
      float rs = 0.f;
#pragma unroll
      for (int mt = 0; mt < 4; ++mt)
#pragma unroll
        for (int rg = 0; rg < 4; ++rg) {
          float p = __expf(fmaf(ST[mt][nt][rg], scale, -mn));
          ST[mt][nt][rg] = p;
          rs += p;
        }
      rs += __shfl_xor(rs, 16, 64);
      rs += __shfl_xor(rs, 32, 64);
      lrow[nt] = lrow[nt] * al[nt] + rs;
    }

    __syncthreads();   // #2: all waves done reading Ks before P^T overwrites it

    // P^T -> LDS [i][j] (j contiguous), packed 4 bf16 per write
#pragma unroll
    for (int nt = 0; nt < 2; ++nt)
#pragma unroll
      for (int mt = 0; mt < 4; ++mt) {
        ushort4 pk;
        pk.x = f2bf(ST[mt][nt][0]);
        pk.y = f2bf(ST[mt][nt][1]);
        pk.z = f2bf(ST[mt][nt][2]);
        pk.w = f2bf(ST[mt][nt][3]);
        *(ushort4*)&KPs[((wid * 2 + nt) * 16 + l15) * 72 + mt * 16 + 4 * q] = pk;
      }

    // O rescale: gather alpha to O's lane mapping (row i = 4q+rg)
    float alo[2][4];
#pragma unroll
    for (int mo = 0; mo < 2; ++mo)
#pragma unroll
      for (int rg = 0; rg < 4; ++rg) alo[mo][rg] = __shfl(al[mo], 4 * q + rg, 64);
#pragma unroll
    for (int mo = 0; mo < 2; ++mo)
#pragma unroll
      for (int cn = 0; cn < 8; ++cn)
#pragma unroll
        for (int rg = 0; rg < 4; ++rg) O[mo][cn][rg] *= alo[mo][rg];

    // O += P . flashV  (A = own P rows from LDS; B = Vs [c][j])
#pragma unroll
    for (int kk = 0; kk < 2; ++kk) {
      bf16x8 Ap[2];
      Ap[0] = *(const bf16x8*)&KPs[(wid * 32 + 0 * 16 + l15) * 72 + kk * 32 + q * 8];
      Ap[1] = *(const bf16x8*)&KPs[(wid * 32 + 1 * 16 + l15) * 72 + kk * 32 + q * 8];
#pragma unroll
      for (int cn = 0; cn < 8; ++cn) {
        bf16x8 Bv = *(const bf16x8*)&Vs[(cn * 16 + l15) * 72 + kk * 32 + q * 8];
        O[0][cn] = MFMA16(Ap[0], Bv, O[0][cn]);
        O[1][cn] = MFMA16(Ap[1], Bv, O[1][cn]);
      }
    }
    __syncthreads();   // #3: before next staging overwrites KPs/Vs
  }

  // epilogue: divide by l (gathered to O lane mapping), transpose via LDS
  float linv[2];
#pragma unroll
  for (int nt = 0; nt < 2; ++nt) linv[nt] = 1.f / lrow[nt];
  float lo[2][4];
#pragma unroll
  for (int mo = 0; mo < 2; ++mo)
#pragma unroll
    for (int rg = 0; rg < 4; ++rg) lo[mo][rg] = __shfl(linv[mo], 4 * q + rg, 64);
#pragma unroll
  for (int mo = 0; mo < 2; ++mo)
#pragma unroll
    for (int rg = 0; rg < 4; ++rg)
#pragma unroll
      for (int cn = 0; cn < 8; ++cn)
        Os[(cn * 16 + l15) * 132 + wid * 32 + mo * 16 + 4 * q + rg] = O[mo][cn][rg] * lo[mo][rg];
  __syncthreads();
  float* obase = out + (size_t)bh * 128 * 2048 + it * 128;
#pragma unroll
  for (int r = 0; r < 16; ++r) {
    int chunk = tid + 256 * r;
    int row = chunk >> 5, ch = chunk & 31;
    *(float4*)&obase[(size_t)row * 2048 + ch * 4] = *(const float4*)&Os[row * 132 + ch * 4];
  }
}

// ---------------------------------------------------------------------------
extern "C" void kernel_launch(void* const* d_in, const int* in_sizes, int n_in,
                              void* d_out, int out_size, void* d_ws, size_t ws_size,
                              hipStream_t stream) {
  const float* x   = (const float*)d_in[0];
  const float* wq  = (const float*)d_in[1];
  const float* bq  = (const float*)d_in[2];
  const float* gw1 = (const float*)d_in[3];
  const float* gb1 = (const float*)d_in[4];
  const float* wk  = (const float*)d_in[5];
  const float* bk  = (const float*)d_in[6];
  const float* gw2 = (const float*)d_in[7];
  const float* gb2 = (const float*)d_in[8];
  const float* wv  = (const float*)d_in[9];
  const float* bv  = (const float*)d_in[10];
  const float* gw3 = (const float*)d_in[11];
  const float* gb3 = (const float*)d_in[12];
  float* out = (float*)d_out;
  char* ws = (char*)d_ws;

  ushort_t* Qb = (ushort_t*)(ws);               // 33,554,432 B  [B,C,P] bf16
  ushort_t* Kb = (ushort_t*)(ws + 33554432);    // 33,554,432 B  [B,H,P,128] bf16
  ushort_t* Vb = (ushort_t*)(ws + 67108864);    // 33,554,432 B  [B,H,P,128] bf16
  float* stats = (float*)(ws + 100663296);      // 768 groups x {s1,s2}

  hipMemsetAsync(stats, 0, 1536 * sizeof(float), stream);
  conv_gn<<<dim3(16, 64), 256, 0, stream>>>(x, wq, wk, wv, bq, bk, bv,
                                            Qb, Kb, Vb, stats);
  gn_apply<<<24576, 256, 0, stream>>>(Qb, stats, gw1, gb1, gw2, gb2, gw3, gb3);
  attn<<<dim3(16, 64), 256, 0, stream>>>(Qb, Kb, Vb, out);
}

// Round 3
// 586.426 us; speedup vs baseline: 1.4169x; 1.4169x over previous
//
#include <hip/hip_runtime.h>

typedef unsigned short ushort_t;
typedef float  f32x4  __attribute__((ext_vector_type(4)));
typedef __bf16 bf16x8 __attribute__((ext_vector_type(8)));

#define MFMA16(a,b,c) __builtin_amdgcn_mfma_f32_16x16x32_bf16((a),(b),(c),0,0,0)

__device__ __forceinline__ ushort_t f2bf(float f) {
  union { float f; unsigned u; } v; v.f = f;
  unsigned u = v.u;
  unsigned r = u + 0x7FFFu + ((u >> 16) & 1u);   // round-to-nearest-even
  return (ushort_t)(r >> 16);
}
__device__ __forceinline__ float bf2f(ushort_t s) {
  union { unsigned u; float f; } v; v.u = ((unsigned)s) << 16;
  return v.f;
}

// ---------------------------------------------------------------------------
// Kernel 1: fused grouped conv (MFMA) + bias; x staged once per block (f32 ->
// bf16 transpose in LDS), loops 3 branches x 4 ngsub. Writes unnormalized y
// in final layouts; accumulates GroupNorm partial sums via atomics.
// grid (pc=16, g*b=64), 256 thr.
// Q branch -> [B][C][P]; K/V branches -> [B][H][P][128].
// ---------------------------------------------------------------------------
__global__ __launch_bounds__(256) void conv_gn(
    const float* __restrict__ x,
    const float* __restrict__ wq, const float* __restrict__ wk, const float* __restrict__ wv,
    const float* __restrict__ bq, const float* __restrict__ bk, const float* __restrict__ bv,
    ushort_t* __restrict__ Qb, ushort_t* __restrict__ Kb, ushort_t* __restrict__ Vb,
    float* __restrict__ stats) {
  int pc = blockIdx.x;
  int gz = blockIdx.y;
  int b = gz & 7, g = gz >> 3;
  int tid = threadIdx.x, lane = tid & 63, wid = tid >> 6;
  int l15 = lane & 15, q = lane >> 4;

  __shared__ __align__(16) ushort_t xl[128 * 72];   // [p][f]
  __shared__ __align__(16) ushort_t wl[128 * 72];   // [co][f], one branch
  __shared__ __align__(16) ushort_t yl[128 * 40];   // staging (br=0 uses [32][136])
  __shared__ float biasl[128];
  __shared__ float redbuf[8];

  // stage x tile [64 f][128 p] f32 -> xl[p][f] bf16
  const float* xsrc = x + ((size_t)(b * 512 + g * 64)) * 2048 + pc * 128;
#pragma unroll
  for (int r = 0; r < 8; ++r) {
    int chunk = tid + 256 * r;
    int c = chunk >> 5, p4 = chunk & 31;
    float4 v = *(const float4*)&xsrc[(size_t)c * 2048 + p4 * 4];
    xl[(p4 * 4 + 0) * 72 + c] = f2bf(v.x);
    xl[(p4 * 4 + 1) * 72 + c] = f2bf(v.y);
    xl[(p4 * 4 + 2) * 72 + c] = f2bf(v.z);
    xl[(p4 * 4 + 3) * 72 + c] = f2bf(v.w);
  }
  __syncthreads();

  // resident B-frags (wave's 32 p-cols)
  bf16x8 Bx[2][2];
#pragma unroll
  for (int n2 = 0; n2 < 2; ++n2)
#pragma unroll
    for (int kk = 0; kk < 2; ++kk)
      Bx[n2][kk] = *(const bf16x8*)&xl[((wid * 2 + n2) * 16 + l15) * 72 + kk * 32 + q * 8];

  for (int br = 0; br < 3; ++br) {
    const float* w    = (br == 0) ? wq : ((br == 1) ? wk : wv);
    const float* bias = (br == 0) ? bq : ((br == 1) ? bk : bv);
    ushort_t* dst     = (br == 0) ? Qb : ((br == 1) ? Kb : Vb);
    __syncthreads();   // previous branch's wl/yl consumers done
    const float* wsrc = w + (size_t)g * 128 * 64;
#pragma unroll
    for (int r = 0; r < 8; ++r) {
      int idx = (tid + 256 * r) << 2;
      float4 v = *(const float4*)&wsrc[idx];
      int row = idx >> 6, f = idx & 63;
      wl[row * 72 + f + 0] = f2bf(v.x);
      wl[row * 72 + f + 1] = f2bf(v.y);
      wl[row * 72 + f + 2] = f2bf(v.z);
      wl[row * 72 + f + 3] = f2bf(v.w);
    }
    if (tid < 128) biasl[tid] = bias[g * 128 + tid];
    __syncthreads();

    for (int ngs = 0; ngs < 4; ++ngs) {
      int co0 = ngs * 32;
      bf16x8 Aw[2][2];
#pragma unroll
      for (int m = 0; m < 2; ++m)
#pragma unroll
        for (int kk = 0; kk < 2; ++kk)
          Aw[m][kk] = *(const bf16x8*)&wl[(co0 + m * 16 + l15) * 72 + kk * 32 + q * 8];
      f32x4 acc[2][2];
#pragma unroll
      for (int m = 0; m < 2; ++m)
#pragma unroll
        for (int n2 = 0; n2 < 2; ++n2) acc[m][n2] = (f32x4){0.f, 0.f, 0.f, 0.f};
#pragma unroll
      for (int kk = 0; kk < 2; ++kk)
#pragma unroll
        for (int n2 = 0; n2 < 2; ++n2)
#pragma unroll
          for (int m = 0; m < 2; ++m)
            acc[m][n2] = MFMA16(Aw[m][kk], Bx[n2][kk], acc[m][n2]);

      float s1 = 0.f, s2 = 0.f;
#pragma unroll
      for (int m = 0; m < 2; ++m)
#pragma unroll
        for (int n2 = 0; n2 < 2; ++n2)
#pragma unroll
          for (int rg = 0; rg < 4; ++rg) {
            float y = acc[m][n2][rg] + biasl[co0 + m * 16 + 4 * q + rg];
            acc[m][n2][rg] = y;
            s1 += y; s2 += y * y;
          }
#pragma unroll
      for (int mask = 32; mask >= 1; mask >>= 1) {
        s1 += __shfl_xor(s1, mask, 64);
        s2 += __shfl_xor(s2, mask, 64);
      }

      __syncthreads();   // previous ngs's yl global-store reads done
      if (lane == 0) { redbuf[wid * 2] = s1; redbuf[wid * 2 + 1] = s2; }
      if (br == 0) {   // yl: [32 c][136 p]
#pragma unroll
        for (int m = 0; m < 2; ++m)
#pragma unroll
          for (int n2 = 0; n2 < 2; ++n2)
#pragma unroll
            for (int rg = 0; rg < 4; ++rg)
              yl[(m * 16 + 4 * q + rg) * 136 + (wid * 2 + n2) * 16 + l15] = f2bf(acc[m][n2][rg]);
      } else {         // yl: [128 p][40 c]
#pragma unroll
        for (int m = 0; m < 2; ++m)
#pragma unroll
          for (int n2 = 0; n2 < 2; ++n2)
#pragma unroll
            for (int rg = 0; rg < 4; ++rg)
              yl[((wid * 2 + n2) * 16 + l15) * 40 + m * 16 + 4 * q + rg] = f2bf(acc[m][n2][rg]);
      }
      __syncthreads();

      if (br == 0) {
#pragma unroll
        for (int r = 0; r < 2; ++r) {
          int chunk = tid + 256 * r;
          int row = chunk >> 4, ch = chunk & 15;
          *(uint4*)&dst[((size_t)(b * 1024 + g * 128 + co0 + row)) * 2048 + pc * 128 + ch * 8] =
              *(const uint4*)&yl[row * 136 + ch * 8];
        }
      } else {
#pragma unroll
        for (int r = 0; r < 2; ++r) {
          int chunk = tid + 256 * r;
          int row = chunk >> 2, ch = chunk & 3;
          *(uint4*)&dst[((size_t)(b * 8 + g) * 2048 + pc * 128 + row) * 128 + co0 + ch * 8] =
              *(const uint4*)&yl[row * 40 + ch * 8];
        }
      }
      if (tid == 0) {
        float S1 = redbuf[0] + redbuf[2] + redbuf[4] + redbuf[6];
        float S2 = redbuf[1] + redbuf[3] + redbuf[5] + redbuf[7];
        int sidx = (br * 8 + b) * 32 + g * 4 + ngs;
        atomicAdd(&stats[2 * sidx], S1);
        atomicAdd(&stats[2 * sidx + 1], S2);
      }
    }
  }
}

// ---------------------------------------------------------------------------
// Kernel 2: in-place GroupNorm affine + LeakyReLU over the 3 contiguous bufs.
// ---------------------------------------------------------------------------
__global__ __launch_bounds__(256) void gn_apply(
    ushort_t* __restrict__ buf, const float* __restrict__ stats,
    const float* __restrict__ gw1, const float* __restrict__ gb1,
    const float* __restrict__ gw2, const float* __restrict__ gb2,
    const float* __restrict__ gw3, const float* __restrict__ gb3) {
  const unsigned NQ = 16777216u;
  unsigned gid = blockIdx.x * 256 + threadIdx.x;
  unsigned e = gid * 8;
  int br; unsigned local;
  if (e < NQ)            { br = 0; local = e; }
  else if (e < 2u * NQ)  { br = 1; local = e - NQ; }
  else                   { br = 2; local = e - 2u * NQ; }
  int b, c0;
  if (br == 0) { b = local >> 21; c0 = (local >> 11) & 1023; }
  else {
    int cih = local & 127; int h = (local >> 18) & 7;
    b = local >> 21; c0 = h * 128 + cih;
  }
  int ng = c0 >> 5;
  const float* gw = (br == 0) ? gw1 : ((br == 1) ? gw2 : gw3);
  const float* gb = (br == 0) ? gb1 : ((br == 1) ? gb2 : gb3);
  int sidx = (br * 8 + b) * 32 + ng;
  float mean = stats[2 * sidx] * (1.f / 65536.f);
  float var  = stats[2 * sidx + 1] * (1.f / 65536.f) - mean * mean;
  float rstd = rsqrtf(var + 1e-5f);
  uint4 d = *(uint4*)&buf[(size_t)e];
  ushort_t* pu = (ushort_t*)&d;
#pragma unroll
  for (int i = 0; i < 8; ++i) {
    int ci = (br == 0) ? c0 : (c0 + i);
    float a = rstd * gw[ci];
    float b2 = gb[ci] - mean * a;
    float yn = fmaf(bf2f(pu[i]), a, b2);
    yn = (yn >= 0.f) ? yn : 0.1f * yn;
    pu[i] = f2bf(yn);
  }
  *(uint4*)&buf[(size_t)e] = d;
}

// ---------------------------------------------------------------------------
// Kernel 3: flash attention (R1 S-formulation, i-tile 64 for 3 blocks/CU).
// flashQ=K-branch [B,H,P,128] (i), flashK=V-branch [B,H,P,128] (j),
// flashV=Q-branch [B,C,P]. i-tile 64 (wave owns 16 i-rows), j-tile 64.
// LDS 53248 B -> 3 blocks/CU. 3 barriers per jt (P is wave-private).
// ---------------------------------------------------------------------------
__global__ __launch_bounds__(256, 3) void attn(
    const ushort_t* __restrict__ Qb, const ushort_t* __restrict__ Kb,
    const ushort_t* __restrict__ Vb, float* __restrict__ out) {
  __shared__ __align__(16) ushort_t smem[26624];   // 53248 B
  ushort_t* Qs  = smem;            // [64 i][136] flashQ tile (resident)
  ushort_t* Vs  = smem + 8704;     // [128 c][72] flashV tile, [c][j]
  ushort_t* KPs = smem + 17920;    // union: Ks [64 j][136] / Ps [64 i][72]
  float* Os = (float*)smem;        // [128 c][68 p] epilogue staging

  int it = blockIdx.x, bh = blockIdx.y;
  int tid = threadIdx.x, lane = tid & 63, wid = tid >> 6;
  int l15 = lane & 15, q = lane >> 4;
  const float scale = 0.08838834764831845f;   // 1/sqrt(128)

  const ushort_t* fQ = Kb + ((size_t)bh * 2048 + it * 64) * 128;
#pragma unroll
  for (int r = 0; r < 4; ++r) {
    int chunk = tid + 256 * r;
    int row = chunk >> 4, ch = chunk & 15;
    *(uint4*)&Qs[row * 136 + ch * 8] = *(const uint4*)&fQ[(size_t)row * 128 + ch * 8];
  }
  __syncthreads();

  bf16x8 Aq[4];   // resident flashQ fragments (wave's 16 i-rows)
#pragma unroll
  for (int kk = 0; kk < 4; ++kk)
    Aq[kk] = *(const bf16x8*)&Qs[(wid * 16 + l15) * 136 + kk * 32 + q * 8];

  float mrow[4], lrow[4];
  f32x4 O[8];
#pragma unroll
  for (int rg = 0; rg < 4; ++rg) { mrow[rg] = -1e30f; lrow[rg] = 0.f; }
#pragma unroll
  for (int cn = 0; cn < 8; ++cn) O[cn] = (f32x4){0.f, 0.f, 0.f, 0.f};

  for (int jt = 0; jt < 32; ++jt) {
    const ushort_t* fK = Vb + ((size_t)bh * 2048 + jt * 64) * 128;
    const ushort_t* fV = Qb + (size_t)bh * 128 * 2048 + jt * 64;
#pragma unroll
    for (int r = 0; r < 4; ++r) {
      int chunk = tid + 256 * r;
      { int row = chunk >> 4, ch = chunk & 15;
        *(uint4*)&KPs[row * 136 + ch * 8] = *(const uint4*)&fK[(size_t)row * 128 + ch * 8]; }
      { int row = chunk >> 3, ch = chunk & 7;
        *(uint4*)&Vs[row * 72 + ch * 8] = *(const uint4*)&fV[(size_t)row * 2048 + ch * 8]; }
    }
    __syncthreads();   // #1 tiles visible

    // S = flashQ . flashK^T
    f32x4 S[4];
#pragma unroll
    for (int n = 0; n < 4; ++n) S[n] = (f32x4){0.f, 0.f, 0.f, 0.f};
#pragma unroll
    for (int kk = 0; kk < 4; ++kk)
#pragma unroll
      for (int n = 0; n < 4; ++n) {
        bf16x8 Bk = *(const bf16x8*)&KPs[(n * 16 + l15) * 136 + kk * 32 + q * 8];
        S[n] = MFMA16(Aq[kk], Bk, S[n]);
      }

    // online softmax (rows i = 4q+rg; cols across l15 + 4 n-tiles)
    float al[4];
#pragma unroll
    for (int rg = 0; rg < 4; ++rg) {
      float v0 = fmaxf(fmaxf(S[0][rg], S[1][rg]), fmaxf(S[2][rg], S[3][rg])) * scale;
      v0 = fmaxf(v0, __shfl_xor(v0, 1, 64));
      v0 = fmaxf(v0, __shfl_xor(v0, 2, 64));
      v0 = fmaxf(v0, __shfl_xor(v0, 4, 64));
      v0 = fmaxf(v0, __shfl_xor(v0, 8, 64));
      float mn = fmaxf(mrow[rg], v0);
      float a = __expf(mrow[rg] - mn);
      mrow[rg] = mn;
      al[rg] = a;
      float rs = 0.f;
#pragma unroll
      for (int n = 0; n < 4; ++n) {
        float p = __expf(fmaf(S[n][rg], scale, -mn));
        S[n][rg] = p;
        rs += p;
      }
      rs += __shfl_xor(rs, 1, 64);
      rs += __shfl_xor(rs, 2, 64);
      rs += __shfl_xor(rs, 4, 64);
      rs += __shfl_xor(rs, 8, 64);
      lrow[rg] = lrow[rg] * a + rs;
    }
#pragma unroll
    for (int cn = 0; cn < 8; ++cn)
#pragma unroll
      for (int rg = 0; rg < 4; ++rg) O[cn][rg] *= al[rg];

    __syncthreads();   // #2 all waves done reading Ks before P overwrites it
#pragma unroll
    for (int n = 0; n < 4; ++n)
#pragma unroll
      for (int rg = 0; rg < 4; ++rg)
        KPs[(wid * 16 + 4 * q + rg) * 72 + n * 16 + l15] = f2bf(S[n][rg]);
    // no barrier: PV reads only this wave's own P rows

    // O += P . flashV  (A = own P rows; B = Vs [c][j])
#pragma unroll
    for (int kk = 0; kk < 2; ++kk) {
      bf16x8 Ap = *(const bf16x8*)&KPs[(wid * 16 + l15) * 72 + kk * 32 + q * 8];
#pragma unroll
      for (int cn = 0; cn < 8; ++cn) {
        bf16x8 Bv = *(const bf16x8*)&Vs[(cn * 16 + l15) * 72 + kk * 32 + q * 8];
        O[cn] = MFMA16(Ap, Bv, O[cn]);
      }
    }
    __syncthreads();   // #3 before next staging overwrites KPs/Vs
  }

  // epilogue: divide by l, transpose via LDS, coalesced store
  float linv[4];
#pragma unroll
  for (int rg = 0; rg < 4; ++rg) linv[rg] = 1.f / lrow[rg];
#pragma unroll
  for (int cn = 0; cn < 8; ++cn)
#pragma unroll
    for (int rg = 0; rg < 4; ++rg)
      Os[(cn * 16 + l15) * 68 + wid * 16 + 4 * q + rg] = O[cn][rg] * linv[rg];
  __syncthreads();
  float* obase = out + (size_t)bh * 128 * 2048 + it * 64;
#pragma unroll
  for (int r = 0; r < 8; ++r) {
    int chunk = tid + 256 * r;
    int row = chunk >> 4, ch = chunk & 15;
    *(float4*)&obase[(size_t)row * 2048 + ch * 4] = *(const float4*)&Os[row * 68 + ch * 4];
  }
}

// ---------------------------------------------------------------------------
extern "C" void kernel_launch(void* const* d_in, const int* in_sizes, int n_in,
                              void* d_out, int out_size, void* d_ws, size_t ws_size,
                              hipStream_t stream) {
  const float* x   = (const float*)d_in[0];
  const float* wq  = (const float*)d_in[1];
  const float* bq  = (const float*)d_in[2];
  const float* gw1 = (const float*)d_in[3];
  const float* gb1 = (const float*)d_in[4];
  const float* wk  = (const float*)d_in[5];
  const float* bk  = (const float*)d_in[6];
  const float* gw2 = (const float*)d_in[7];
  const float* gb2 = (const float*)d_in[8];
  const float* wv  = (const float*)d_in[9];
  const float* bv  = (const float*)d_in[10];
  const float* gw3 = (const float*)d_in[11];
  const float* gb3 = (const float*)d_in[12];
  float* out = (float*)d_out;
  char* ws = (char*)d_ws;

  ushort_t* Qb = (ushort_t*)(ws);               // 33,554,432 B  [B,C,P] bf16
  ushort_t* Kb = (ushort_t*)(ws + 33554432);    // 33,554,432 B  [B,H,P,128] bf16
  ushort_t* Vb = (ushort_t*)(ws + 67108864);    // 33,554,432 B  [B,H,P,128] bf16
  float* stats = (float*)(ws + 100663296);      // 768 groups x {s1,s2}

  hipMemsetAsync(stats, 0, 1536 * sizeof(float), stream);
  conv_gn<<<dim3(16, 64), 256, 0, stream>>>(x, wq, wk, wv, bq, bk, bv,
                                            Qb, Kb, Vb, stats);
  gn_apply<<<24576, 256, 0, stream>>>(Qb, stats, gw1, gb1, gw2, gb2, gw3, gb3);
  attn<<<dim3(32, 64), 256, 0, stream>>>(Qb, Kb, Vb, out);
}